// Round 2
// baseline (686.034 us; speedup 1.0000x reference)
//
#include <hip/hip_runtime.h>
#include <hip/hip_bf16.h>

// SparseMLP: per-expert  out = gelu_tanh(x @ w1^T) @ w2
// E=8, T=2048, H=1024, F=4096. fp32 in/out, bf16 MFMA compute.
//
// R2: XOR-swizzled LDS. R3: 32x32x16 MFMA + XCD raster (GEMM ~199us each).
// R4: 8-phase 256^2 port FAILED (239us/GEMM, MfmaUtil 24%): at 1 block/CU the
//     lockstep {drain->MFMA} phases expose ~2.2x structural stall (LDS-drain
//     serialization + frag-reg WAR + 8 barrier skews/kt); R3's 3-blocks/CU
//     inter-block overlap is worth more. BUT R4's transpose_cast (64-row
//     tiles, ushort2 stores) cut preamble 278->189us.
// R5: bank the decomposition: R3 GEMMs (proven 199us) + R4 preamble.

typedef __bf16 bf16x8 __attribute__((ext_vector_type(8)));
typedef float  f32x16 __attribute__((ext_vector_type(16)));

__device__ inline unsigned short f2b(float f) {
    unsigned u = __float_as_uint(f);
    u += 0x7fff + ((u >> 16) & 1);   // round-to-nearest-even
    return (unsigned short)(u >> 16);
}

// ---------------- cast fp32 -> bf16 (flat, vectorized) ----------------
__global__ void cast_f32_bf16(const float* __restrict__ in,
                              unsigned short* __restrict__ out, int n4) {
    int i = blockIdx.x * 256 + threadIdx.x;
    if (i >= n4) return;
    float4 v = ((const float4*)in)[i];
    ushort4 o;
    o.x = f2b(v.x); o.y = f2b(v.y); o.z = f2b(v.z); o.w = f2b(v.w);
    ((ushort4*)out)[i] = o;
}

// ------------- transpose-cast w2: fp32 [E,F,H] -> bf16 [E,H,F] -------------
// 64(f) x 32(h) tile; ushort2 stores -> fully-coalesced writes.
__global__ void transpose_cast(const float* __restrict__ in,
                               unsigned short* __restrict__ out, int F, int H) {
    __shared__ float tile[64][33];
    const int e = blockIdx.z;
    const int f0 = blockIdx.y * 64, h0 = blockIdx.x * 32;
    const float* src = in + (long long)e * F * H;
    unsigned short* dst = out + (long long)e * F * H;
    const int tx = threadIdx.x, ty = threadIdx.y;   // 32 x 8
#pragma unroll
    for (int i = 0; i < 64; i += 8)
        tile[ty + i][tx] = src[(long long)(f0 + ty + i) * H + h0 + tx];
    __syncthreads();
#pragma unroll
    for (int i = 0; i < 32; i += 8) {
        const int h = ty + i;
        ushort2 o;
        o.x = f2b(tile[2 * tx][h]);
        o.y = f2b(tile[2 * tx + 1][h]);
        *(ushort2*)&dst[(long long)(h0 + h) * F + f0 + 2 * tx] = o;
    }
}

// ---------------- bf16 GEMM, C = A @ B^T, swizzled LDS, 32x32x16 MFMA ----------
// A: [E][M][K] bf16 (K-major), B: [E][N][K] bf16 (K-major), C: [E][M][N]
// 128x128 tile, BK=64, 256 threads (4 waves), wave computes 64x64 (2x2 of 32x32).
// LDS tile: [128 rows][8 chunks of 8 bf16]; physical chunk = logical ^ (row&7).
// RASTER1D (GEMM2): 1D grid, XCD = id&7 owns y-tiles {2*xcd, 2*xcd+1} so its
// two 1MB A-slabs pin in the 4MB per-XCD L2.
template <bool GELU, bool RASTER1D, typename CT>
__global__ __launch_bounds__(256) void gemm_bt(
    const unsigned short* __restrict__ A,
    const unsigned short* __restrict__ B,
    CT* __restrict__ C, int M, int N, int K) {
    int e, bm, bn;
    if constexpr (RASTER1D) {
        // grid = E*16*8 blocks; decode: XCD (id&7) -> y-pair, t&7 -> x-tile
        const int id = blockIdx.x;
        const int xcd = id & 7, s = id >> 3, t = s & 15;
        e  = s >> 4;
        bm = (xcd * 2 + (t >> 3)) * 128;
        bn = (t & 7) * 128;
    } else {
        e = blockIdx.z; bm = blockIdx.y * 128; bn = blockIdx.x * 128;
    }
    A += (long long)e * M * K;
    B += (long long)e * N * K;
    C += (long long)e * M * N;

    __shared__ unsigned short sA[128 * 64];
    __shared__ unsigned short sB[128 * 64];

    const int tid  = threadIdx.x;
    const int lane = tid & 63;
    const int wave = tid >> 6;
    const int half = lane >> 5, r32 = lane & 31;
    const int wm = (wave & 1) * 64, wn = (wave >> 1) * 64;

    f32x16 acc[2][2] = {};

    for (int k0 = 0; k0 < K; k0 += 64) {
        // ---- stage A,B tiles (128x64 bf16) via async global->LDS, 16B/lane.
        // LDS dest lane-contiguous (required); swizzle applied on global src.
#pragma unroll
        for (int r = 0; r < 4; ++r) {
            const int eoff = r * 2048 + tid * 8;       // dest element offset
            const int row = eoff >> 6;
            const int cD  = (eoff >> 3) & 7;           // dest chunk
            const int scol = ((cD ^ (row & 7)) << 3);  // swizzled source column
            const unsigned short* ga = A + (long long)(bm + row) * K + k0 + scol;
            const unsigned short* gb = B + (long long)(bn + row) * K + k0 + scol;
            __builtin_amdgcn_global_load_lds(
                (const __attribute__((address_space(1))) void*)ga,
                (__attribute__((address_space(3))) void*)(&sA[eoff]), 16, 0, 0);
            __builtin_amdgcn_global_load_lds(
                (const __attribute__((address_space(1))) void*)gb,
                (__attribute__((address_space(3))) void*)(&sB[eoff]), 16, 0, 0);
        }
        __syncthreads();

        // ---- 4 x (K=16) MFMA steps, 32x32x16 ----
#pragma unroll
        for (int ks = 0; ks < 4; ++ks) {
            bf16x8 af[2], bfr[2];
            const int cL = ks * 2 + half;              // logical chunk
#pragma unroll
            for (int i = 0; i < 2; ++i) {
                const int ra = wm + i * 32 + r32;
                const int rb = wn + i * 32 + r32;
                af[i]  = *(const bf16x8*)&sA[ra * 64 + ((cL ^ (ra & 7)) << 3)];
                bfr[i] = *(const bf16x8*)&sB[rb * 64 + ((cL ^ (rb & 7)) << 3)];
            }
#pragma unroll
            for (int i = 0; i < 2; ++i)
#pragma unroll
                for (int j = 0; j < 2; ++j)
                    acc[i][j] = __builtin_amdgcn_mfma_f32_32x32x16_bf16(
                        af[i], bfr[j], acc[i][j], 0, 0, 0);
        }
        __syncthreads();
    }

    // ---- epilogue: 32x32 C/D layout col=lane&31, row=(r&3)+8*(r>>2)+4*half ----
#pragma unroll
    for (int i = 0; i < 2; ++i) {
        const int row_base = bm + wm + i * 32;
#pragma unroll
        for (int j = 0; j < 2; ++j) {
            const int col = bn + wn + j * 32 + r32;
#pragma unroll
            for (int r = 0; r < 16; ++r) {
                const int row = row_base + (r & 3) + 8 * (r >> 2) + 4 * half;
                float v = acc[i][j][r];
                if (GELU) {
                    // gelu_tanh(v) = v * sigmoid(2*0.79788456*(v + 0.044715 v^3))
                    float t = 1.5957691216057308f * (v + 0.044715f * v * v * v);
                    v = v / (1.0f + __expf(-t));
                }
                if constexpr (sizeof(CT) == 2) {
                    ((unsigned short*)C)[(long long)row * N + col] = f2b(v);
                } else {
                    ((float*)C)[(long long)row * N + col] = v;
                }
            }
        }
    }
}

extern "C" void kernel_launch(void* const* d_in, const int* in_sizes, int n_in,
                              void* d_out, int out_size, void* d_ws, size_t ws_size,
                              hipStream_t stream) {
    constexpr int E = 8, T = 2048, H = 1024, F = 4096;
    const float* x  = (const float*)d_in[0];   // [E,T,H]
    const float* w1 = (const float*)d_in[1];   // [E,F,H]
    const float* w2 = (const float*)d_in[2];   // [E,F,H]
    float* out = (float*)d_out;                // [E,T,H]

    unsigned short* xb  = (unsigned short*)d_ws;          // E*T*H bf16
    unsigned short* w1b = xb  + (size_t)E * T * H;        // E*F*H bf16
    unsigned short* w2t = w1b + (size_t)E * F * H;        // E*H*F bf16 (transposed)
    unsigned short* ab  = w2t + (size_t)E * F * H;        // E*T*F bf16 (gelu act)

    const int nx = E * T * H / 4, nw = E * F * H / 4;
    cast_f32_bf16<<<(nx + 255) / 256, 256, 0, stream>>>(x, xb, nx);
    cast_f32_bf16<<<(nw + 255) / 256, 256, 0, stream>>>(w1, w1b, nw);
    transpose_cast<<<dim3(H / 32, F / 64, E), dim3(32, 8), 0, stream>>>(w2, w2t, F, H);

    // GEMM1: a = gelu(x @ w1^T)   [M=T, N=F, K=H] -> bf16 (natural raster:
    // XCD==x%8 partitions B-slices per XCD, A-slab broadcast -> L2-friendly)
    gemm_bt<true, false, unsigned short>
        <<<dim3(F / 128, T / 128, E), 256, 0, stream>>>(xb, w1b, ab, T, F, H);
    // GEMM2: out = a @ w2t^T      [M=T, N=H, K=F] -> fp32 (1D XCD raster)
    gemm_bt<false, true, float>
        <<<dim3(E * (T / 128) * (H / 128)), 256, 0, stream>>>(ab, w2t, out, T, H, F);
}

// Round 3
// 640.856 us; speedup vs baseline: 1.0705x; 1.0705x over previous
//
#include <hip/hip_runtime.h>
#include <hip/hip_bf16.h>

// SparseMLP: per-expert  out = gelu_tanh(x @ w1^T) @ w2
// E=8, T=2048, H=1024, F=4096. fp32 in/out, bf16 MFMA compute.
//
// R3: 128^2 tile, 32x32x16 MFMA, swizzled LDS, 2-barrier loop: ~200us/GEMM,
//     MfmaUtil 30, VALUBusy 33 (> Mfma: 64-bit staging addr math is the
//     largest VALU consumer).
// R4: lockstep 8-barrier/kt 256^2 port FAILED (239us): per-phase
//     {ds_read->lgk0->MFMA} serialization.
// R6 (this): A/B split.
//   GEMM1 = R3 + VALU diet (staging pointers hoisted, +=64/kt).
//   GEMM2 = gemm_ra: 256^2, 8 waves, READ-AHEAD schedule, 2 barriers/kt:
//     frags for phase k loaded in k-1 (af single-buffered: qm0 set loaded at
//     kt boundary, qm1 set reloaded serially in P3 -> 64 frag VGPR, fits
//     2 waves/SIMD with 128 AGPR acc); STG A(kt+1) in P1/P2, B(kt+2) in
//     P3/P4; one vmcnt(4) per kt (B(kt+2) stays in flight across the
//     boundary barrier -- T4). Hazards:
//       sA[p^1] WAR: last readers (P3 af-reads, kt-1) drain via own lgk
//         before boundary barrier < STG-A writes. OK.
//       sB[p]  WAR: last readers (bf1 @P1) drain via P2-entry lgk before
//         P2-end barrier < STG-B writes. OK.
//       RAW: A(kt+1),B(kt+1) drained by boundary vmcnt(4)+barrier before
//         Pb reads them. OK.

typedef __bf16 bf16x8 __attribute__((ext_vector_type(8)));
typedef float  f32x16 __attribute__((ext_vector_type(16)));

__device__ inline unsigned short f2b(float f) {
    unsigned u = __float_as_uint(f);
    u += 0x7fff + ((u >> 16) & 1);   // round-to-nearest-even
    return (unsigned short)(u >> 16);
}

// ---------------- fused cast fp32 -> bf16 for two arrays ----------------
__global__ void cast2_f32_bf16(const float* __restrict__ a,
                               unsigned short* __restrict__ oa, int na4,
                               const float* __restrict__ b,
                               unsigned short* __restrict__ ob, int nb4) {
    int i = blockIdx.x * 256 + threadIdx.x;
    const float4* src;
    ushort4* dst;
    if (i < na4) {
        src = (const float4*)a + i;
        dst = (ushort4*)oa + i;
    } else {
        i -= na4;
        if (i >= nb4) return;
        src = (const float4*)b + i;
        dst = (ushort4*)ob + i;
    }
    float4 v = *src;
    ushort4 o;
    o.x = f2b(v.x); o.y = f2b(v.y); o.z = f2b(v.z); o.w = f2b(v.w);
    *dst = o;
}

// ------------- transpose-cast w2: fp32 [E,F,H] -> bf16 [E,H,F] -------------
__global__ void transpose_cast(const float* __restrict__ in,
                               unsigned short* __restrict__ out, int F, int H) {
    __shared__ float tile[64][33];
    const int e = blockIdx.z;
    const int f0 = blockIdx.y * 64, h0 = blockIdx.x * 32;
    const float* src = in + (long long)e * F * H;
    unsigned short* dst = out + (long long)e * F * H;
    const int tx = threadIdx.x, ty = threadIdx.y;   // 32 x 8
#pragma unroll
    for (int i = 0; i < 64; i += 8)
        tile[ty + i][tx] = src[(long long)(f0 + ty + i) * H + h0 + tx];
    __syncthreads();
#pragma unroll
    for (int i = 0; i < 32; i += 8) {
        const int h = ty + i;
        ushort2 o;
        o.x = f2b(tile[2 * tx][h]);
        o.y = f2b(tile[2 * tx + 1][h]);
        *(ushort2*)&dst[(long long)(h0 + h) * F + f0 + 2 * tx] = o;
    }
}

// ---------------- GEMM1 kernel: R3 + VALU diet ----------------
// 128x128 tile, BK=64, 4 waves, 32x32x16 MFMA, single-buffer LDS.
template <bool GELU, typename CT>
__global__ __launch_bounds__(256, 3) void gemm_bt(
    const unsigned short* __restrict__ A,
    const unsigned short* __restrict__ B,
    CT* __restrict__ C, int M, int N, int K) {
    const int e = blockIdx.z;
    const int bm = blockIdx.y * 128, bn = blockIdx.x * 128;
    A += (long long)e * M * K;
    B += (long long)e * N * K;
    C += (long long)e * M * N;

    __shared__ unsigned short sA[128 * 64];
    __shared__ unsigned short sB[128 * 64];

    const int tid  = threadIdx.x;
    const int lane = tid & 63;
    const int wave = tid >> 6;
    const int half = lane >> 5, r32 = lane & 31;
    const int wm = (wave & 1) * 64, wn = (wave >> 1) * 64;

    // Hoisted staging pointers (advanced by 64 per K-step) -- kills the
    // per-kt 64-bit address rebuild that dominated VALUBusy.
    const unsigned short* ga[4];
    const unsigned short* gb[4];
#pragma unroll
    for (int r = 0; r < 4; ++r) {
        const int eoff = r * 2048 + tid * 8;
        const int row = eoff >> 6;
        const int cD  = (eoff >> 3) & 7;
        const int scol = ((cD ^ (row & 7)) << 3);
        ga[r] = A + (long long)(bm + row) * K + scol;
        gb[r] = B + (long long)(bn + row) * K + scol;
    }

    f32x16 acc[2][2] = {};

    for (int k0 = 0; k0 < K; k0 += 64) {
#pragma unroll
        for (int r = 0; r < 4; ++r) {
            const int eoff = r * 2048 + tid * 8;
            __builtin_amdgcn_global_load_lds(
                (const __attribute__((address_space(1))) void*)ga[r],
                (__attribute__((address_space(3))) void*)(&sA[eoff]), 16, 0, 0);
            __builtin_amdgcn_global_load_lds(
                (const __attribute__((address_space(1))) void*)gb[r],
                (__attribute__((address_space(3))) void*)(&sB[eoff]), 16, 0, 0);
            ga[r] += 64; gb[r] += 64;
        }
        __syncthreads();

#pragma unroll
        for (int ks = 0; ks < 4; ++ks) {
            bf16x8 af[2], bfr[2];
            const int cL = ks * 2 + half;
#pragma unroll
            for (int i = 0; i < 2; ++i) {
                const int ra = wm + i * 32 + r32;
                const int rb = wn + i * 32 + r32;
                af[i]  = *(const bf16x8*)&sA[ra * 64 + ((cL ^ (ra & 7)) << 3)];
                bfr[i] = *(const bf16x8*)&sB[rb * 64 + ((cL ^ (rb & 7)) << 3)];
            }
#pragma unroll
            for (int i = 0; i < 2; ++i)
#pragma unroll
                for (int j = 0; j < 2; ++j)
                    acc[i][j] = __builtin_amdgcn_mfma_f32_32x32x16_bf16(
                        af[i], bfr[j], acc[i][j], 0, 0, 0);
        }
        __syncthreads();
    }

#pragma unroll
    for (int i = 0; i < 2; ++i) {
        const int row_base = bm + wm + i * 32;
#pragma unroll
        for (int j = 0; j < 2; ++j) {
            const int col = bn + wn + j * 32 + r32;
#pragma unroll
            for (int r = 0; r < 16; ++r) {
                const int row = row_base + (r & 3) + 8 * (r >> 2) + 4 * half;
                float v = acc[i][j][r];
                if (GELU) {
                    float t = 1.5957691216057308f * (v + 0.044715f * v * v * v);
                    v = v / (1.0f + __expf(-t));
                }
                if constexpr (sizeof(CT) == 2) {
                    ((unsigned short*)C)[(long long)row * N + col] = f2b(v);
                } else {
                    ((float*)C)[(long long)row * N + col] = v;
                }
            }
        }
    }
}

// ---------------- GEMM2 kernel: 256^2 read-ahead, 2 barriers/kt ----------
// A:[E][M][K], B:[E][N][K] bf16 K-major; C fp32. 512 thr = 8 waves (2M x 4N),
// wave owns 128x64 (4 msub x 2 nsub of 32x32). LDS 128KB double-buffered.
#define STG(dst, ptr, q)                                                      \
    __builtin_amdgcn_global_load_lds(                                         \
        (const __attribute__((address_space(1))) void*)(ptr),                 \
        (__attribute__((address_space(3))) void*)(&(dst)[(q) * 4096 + sdst]), \
        16, 0, 0)
#define LGK0 do { asm volatile("s_waitcnt lgkmcnt(0)" ::: "memory");          \
                  __builtin_amdgcn_sched_barrier(0); } while (0)

template <bool GELU, typename CT>
__global__ __launch_bounds__(512) void gemm_ra(
    const unsigned short* __restrict__ A,
    const unsigned short* __restrict__ B,
    CT* __restrict__ C, int M, int N, int K) {
    // XCD-chunked bijective raster (nwg % 8 == 0)
    const int nwg = gridDim.x;
    const int id = blockIdx.x;
    const int wgid = (id & 7) * (nwg >> 3) + (id >> 3);
    const int ntn = N >> 8;
    const int tpe = (M >> 8) * ntn;
    const int e = wgid / tpe;
    const int rem = wgid - e * tpe;
    const int bm = (rem / ntn) << 8;
    const int bn = (rem % ntn) << 8;
    A += (long long)e * M * K;
    B += (long long)e * N * K;
    C += (long long)e * M * N;

    __shared__ __align__(16) unsigned short sA[2][16384];
    __shared__ __align__(16) unsigned short sB[2][16384];

    const int tid = threadIdx.x;
    const int lane = tid & 63;
    const int wid = tid >> 6;
    const int half = lane >> 5, r32 = lane & 31;
    const int wm = (wid >> 2) * 128;
    const int wn = (wid & 3) * 64;

    const int srow = tid >> 3;                             // 0..63
    const int scol = ((tid & 7) ^ ((tid >> 3) & 7)) << 3;  // swizzled src col
    const int sdst = tid * 8;

    // staging cursors: pA -> kt+1 columns, pB -> kt+2 columns
    const unsigned short* pA[4];
    const unsigned short* pB[4];
#pragma unroll
    for (int q = 0; q < 4; ++q) {
        pA[q] = A + (long long)(bm + q * 64 + srow) * K + scol;
        pB[q] = B + (long long)(bn + q * 64 + srow) * K + scol;
    }
    const int NT = K >> 6;

    // ---- prologue: stage A(0), B(0), B(1); leave B(1) in flight (vmcnt 4)
    STG(sA[0], pA[0], 0); STG(sA[0], pA[1], 1);
    STG(sA[0], pA[2], 2); STG(sA[0], pA[3], 3);
    STG(sB[0], pB[0], 0); STG(sB[0], pB[1], 1);
    STG(sB[0], pB[2], 2); STG(sB[0], pB[3], 3);
    if (NT > 1) {
#pragma unroll
        for (int q = 0; q < 4; ++q) STG(sB[1], pB[q] + 64, q);
        asm volatile("s_waitcnt vmcnt(4)" ::: "memory");
    } else {
        asm volatile("s_waitcnt vmcnt(0)" ::: "memory");
    }
#pragma unroll
    for (int q = 0; q < 4; ++q) { pA[q] += 64; pB[q] += 128; }
    __builtin_amdgcn_s_barrier();

    f32x16 acc[4][2] = {};
    bf16x8 af[2][4], bf0[4], bf1[4];

    // ---- Pb(prologue): read af(qm0) + bf0 for kt=0
#pragma unroll
    for (int m = 0; m < 2; ++m) {
        const int row = wm + m * 32 + r32;
#pragma unroll
        for (int ks = 0; ks < 4; ++ks)
            af[m][ks] = *(const bf16x8*)
                &sA[0][row * 64 + (((ks * 2 + half) ^ (row & 7)) << 3)];
    }
    {
        const int row = wn + r32;
#pragma unroll
        for (int ks = 0; ks < 4; ++ks)
            bf0[ks] = *(const bf16x8*)
                &sB[0][row * 64 + (((ks * 2 + half) ^ (row & 7)) << 3)];
    }

    for (int kt = 0; kt < NT; ++kt) {
        const int p = kt & 1;
        const bool pfA = (kt + 1 < NT), pfB = (kt + 2 < NT);
        unsigned short* nA = sA[p ^ 1];
        unsigned short* stB = sB[p];

        // ---- P1: MFMA(af x bf0 -> acc[0..1][0]); read bf1; STG A q0,q1
        LGK0;
        __builtin_amdgcn_s_setprio(1);
#pragma unroll
        for (int ks = 0; ks < 4; ++ks)
#pragma unroll
            for (int m = 0; m < 2; ++m)
                acc[m][0] = __builtin_amdgcn_mfma_f32_32x32x16_bf16(
                    af[m][ks], bf0[ks], acc[m][0], 0, 0, 0);
        __builtin_amdgcn_s_setprio(0);
        {
            const int row = wn + 32 + r32;
#pragma unroll
            for (int ks = 0; ks < 4; ++ks)
                bf1[ks] = *(const bf16x8*)
                    &sB[p][row * 64 + (((ks * 2 + half) ^ (row & 7)) << 3)];
        }
        if (pfA) { STG(nA, pA[0], 0); STG(nA, pA[1], 1); }

        // ---- P2: MFMA(af x bf1 -> acc[0..1][1]); STG A q2,q3; barrier
        LGK0;
        __builtin_amdgcn_s_setprio(1);
#pragma unroll
        for (int ks = 0; ks < 4; ++ks)
#pragma unroll
            for (int m = 0; m < 2; ++m)
                acc[m][1] = __builtin_amdgcn_mfma_f32_32x32x16_bf16(
                    af[m][ks], bf1[ks], acc[m][1], 0, 0, 0);
        __builtin_amdgcn_s_setprio(0);
        if (pfA) { STG(nA, pA[2], 2); STG(nA, pA[3], 3); }
        __builtin_amdgcn_s_barrier();   // all sB[p] readers retired -> STG-B ok

        // ---- P3: reload af(qm1) (serial); STG B q0,q1; MFMA -> acc[2..3][0]
#pragma unroll
        for (int m = 0; m < 2; ++m) {
            const int row = wm + 64 + m * 32 + r32;
#pragma unroll
            for (int ks = 0; ks < 4; ++ks)
                af[m][ks] = *(const bf16x8*)
                    &sA[p][row * 64 + (((ks * 2 + half) ^ (row & 7)) << 3)];
        }
        if (pfB) { STG(stB, pB[0], 0); STG(stB, pB[1], 1); }
        LGK0;
        __builtin_amdgcn_s_setprio(1);
#pragma unroll
        for (int ks = 0; ks < 4; ++ks)
#pragma unroll
            for (int m = 0; m < 2; ++m)
                acc[2 + m][0] = __builtin_amdgcn_mfma_f32_32x32x16_bf16(
                    af[m][ks], bf0[ks], acc[2 + m][0], 0, 0, 0);
        __builtin_amdgcn_s_setprio(0);

        // ---- P4: MFMA(af x bf1 -> acc[2..3][1]); STG B q2,q3; vmcnt; barrier
        __builtin_amdgcn_s_setprio(1);
#pragma unroll
        for (int ks = 0; ks < 4; ++ks)
#pragma unroll
            for (int m = 0; m < 2; ++m)
                acc[2 + m][1] = __builtin_amdgcn_mfma_f32_32x32x16_bf16(
                    af[m][ks], bf1[ks], acc[2 + m][1], 0, 0, 0);
        __builtin_amdgcn_s_setprio(0);
        if (pfB) { STG(stB, pB[2], 2); STG(stB, pB[3], 3); }
        // Boundary: drain A(kt+1)+B(kt+1); keep B(kt+2)'s 4 loads in flight.
        if (pfB) asm volatile("s_waitcnt vmcnt(4)" ::: "memory");
        else     asm volatile("s_waitcnt vmcnt(0)" ::: "memory");
        __builtin_amdgcn_s_barrier();

        // ---- Pb: boundary reads for kt+1 (af qm0 + bf0 from buf p^1)
        if (pfA) {
            const unsigned short* cA = sA[p ^ 1];
            const unsigned short* cB = sB[p ^ 1];
#pragma unroll
            for (int m = 0; m < 2; ++m) {
                const int row = wm + m * 32 + r32;
#pragma unroll
                for (int ks = 0; ks < 4; ++ks)
                    af[m][ks] = *(const bf16x8*)
                        &cA[row * 64 + (((ks * 2 + half) ^ (row & 7)) << 3)];
            }
            const int row = wn + r32;
#pragma unroll
            for (int ks = 0; ks < 4; ++ks)
                bf0[ks] = *(const bf16x8*)
                    &cB[row * 64 + (((ks * 2 + half) ^ (row & 7)) << 3)];
#pragma unroll
            for (int q = 0; q < 4; ++q) { pA[q] += 64; pB[q] += 64; }
        }
    }

    // ---- epilogue (32x32 C/D layout: col=lane&31, row=(r&3)+8*(r>>2)+4*half)
#pragma unroll
    for (int mb = 0; mb < 4; ++mb) {
        const int row_base = bm + wm + mb * 32;
#pragma unroll
        for (int nb = 0; nb < 2; ++nb) {
            const int col = bn + wn + nb * 32 + r32;
#pragma unroll
            for (int r = 0; r < 16; ++r) {
                const int row = row_base + (r & 3) + 8 * (r >> 2) + 4 * half;
                float v = acc[mb][nb][r];
                if (GELU) {
                    float t = 1.5957691216057308f * (v + 0.044715f * v * v * v);
                    v = v / (1.0f + __expf(-t));
                }
                if constexpr (sizeof(CT) == 2) {
                    ((unsigned short*)C)[(long long)row * N + col] = f2b(v);
                } else {
                    ((float*)C)[(long long)row * N + col] = v;
                }
            }
        }
    }
}
#undef STG
#undef LGK0

extern "C" void kernel_launch(void* const* d_in, const int* in_sizes, int n_in,
                              void* d_out, int out_size, void* d_ws, size_t ws_size,
                              hipStream_t stream) {
    constexpr int E = 8, T = 2048, H = 1024, F = 4096;
    const float* x  = (const float*)d_in[0];   // [E,T,H]
    const float* w1 = (const float*)d_in[1];   // [E,F,H]
    const float* w2 = (const float*)d_in[2];   // [E,F,H]
    float* out = (float*)d_out;                // [E,T,H]

    unsigned short* xb  = (unsigned short*)d_ws;          // E*T*H bf16
    unsigned short* w1b = xb  + (size_t)E * T * H;        // E*F*H bf16
    unsigned short* w2t = w1b + (size_t)E * F * H;        // E*H*F bf16 (transposed)
    unsigned short* ab  = w2t + (size_t)E * F * H;        // E*T*F bf16 (gelu act)

    const int nx = E * T * H / 4, nw = E * F * H / 4;
    cast2_f32_bf16<<<(nx + nw + 255) / 256, 256, 0, stream>>>(x, xb, nx, w1, w1b, nw);
    transpose_cast<<<dim3(H / 32, F / 64, E), dim3(32, 8), 0, stream>>>(w2, w2t, F, H);

    // GEMM1: a = gelu(x @ w1^T)   [M=T, N=F, K=H] -> bf16 (R3 + VALU diet)
    gemm_bt<true, unsigned short>
        <<<dim3(F / 128, T / 128, E), 256, 0, stream>>>(xb, w1b, ab, T, F, H);
    // GEMM2: out = a @ w2t^T      [M=T, N=H, K=F] -> fp32 (read-ahead 256^2)
    gemm_ra<false, float>
        <<<dim3(E * (T / 256) * (H / 256)), 512, 0, stream>>>(ab, w2t, out, T, H, F);
}